// Round 3
// baseline (542.557 us; speedup 1.0000x reference)
//
#include <hip/hip_runtime.h>
#include <hip/hip_bf16.h>
#include <math.h>

// Problem constants (fixed by setup_inputs)
#define BB 4
#define TPP 4
#define TFF 2
#define NIMG (BB*TPP)   // 16
#define NF (BB*TFF)     // 8

// async global->LDS copy, 16B per lane; LDS dest = wave-uniform base + lane*16
#define GLL(gaddr, laddr) __builtin_amdgcn_global_load_lds( \
    (const __attribute__((address_space(1))) void*)(gaddr), \
    (__attribute__((address_space(3))) void*)(laddr), 16, 0, 0)

// ---------------------------------------------------------------------------
// Tiny kernel: replicate _interp_indices on device + mark needed past frames.
// ---------------------------------------------------------------------------
__global__ void idx_kernel(const int* __restrict__ pci, const int* __restrict__ fci,
                           int* __restrict__ idx, int* __restrict__ needed)
{
    if (threadIdx.x == 0 && blockIdx.x == 0) {
        for (int n = 0; n < BB*TPP; n++) needed[n] = 0;
        for (int i = 0; i < BB; i++) {
            needed[i*TPP + TPP-1] = 1;              // f1 frame always needed
            int p_pos = TPP - 2;
            for (int j = 0; j < TFF; j++) {
                int f = fci[i*TFF + j];
                while (p_pos >= 0) {
                    if (p_pos == 0 || f < -pci[i*TPP + p_pos - 1]) {
                        idx[i*TFF + j] = p_pos + i*TPP;
                        needed[p_pos + i*TPP] = 1;
                        break;
                    }
                    p_pos--;
                }
            }
        }
    }
}

// ---------------------------------------------------------------------------
// Weight prep: Wt[c][d] = W[d][c] * (g[d]*rsqrt(v[d]+eps)).  32x32 LDS tiles,
// coalesced both sides.  Makes conv A-staging a contiguous row copy.
// ---------------------------------------------------------------------------
template<int C>
__device__ __forceinline__ void wtile(const float* __restrict__ w,
                                      const float* __restrict__ g,
                                      const float* __restrict__ v,
                                      float* __restrict__ wt, int rel)
{
    constexpr int TPR = C/32;
    const int trow = rel / TPR;
    const int tcol = rel % TPR;
    const int tx = threadIdx.x & 31;
    const int ty = threadIdx.x >> 5;     // 0..7
    __shared__ float T[32][33];
    #pragma unroll
    for (int j = 0; j < 4; j++) {
        int d = trow*32 + ty + j*8;
        int c = tcol*32 + tx;
        float sc = g[d] * rsqrtf(v[d] + 1e-5f);
        T[ty + j*8][tx] = w[(size_t)d*C + c] * sc;
    }
    __syncthreads();
    #pragma unroll
    for (int j = 0; j < 4; j++) {
        int c = tcol*32 + ty + j*8;
        int d = trow*32 + tx;
        wt[(size_t)c*C + d] = T[tx][ty + j*8];
    }
}

__global__ __launch_bounds__(256)
void wprep_kernel(const float* w0, const float* g0, const float* v0, float* wt0,
                  const float* w1, const float* g1, const float* v1, float* wt1,
                  const float* w2, const float* g2, const float* v2, float* wt2)
{
    int bid = blockIdx.x;
    if (bid < 16)       wtile<128>(w0, g0, v0, wt0, bid);
    else if (bid < 80)  wtile<256>(w1, g1, v1, wt1, bid - 16);
    else                wtile<512>(w2, g2, v2, wt2, bid - 80);
}

// ---------------------------------------------------------------------------
// Fused conv (all 3 levels, one dispatch).  Per block: 128(d) x 128(p) tile,
// K-tile 16, double-buffered LDS filled via async global_load_lds.
// Scale is folded into Wt; epilogue adds sh[d] = b - m*sc and applies SiLU.
// ---------------------------------------------------------------------------
template<int C, int HW>
__device__ __forceinline__ void conv_tile(
    const float* __restrict__ x, const float* __restrict__ wt,
    const float* __restrict__ g, const float* __restrict__ bb,
    const float* __restrict__ mm, const float* __restrict__ vv,
    float* __restrict__ pf, int n, int dblk, int pblk,
    float* __restrict__ As, float* __restrict__ Bs)
{
    const int tid  = threadIdx.x;
    const int lane = tid & 63;
    const int wv   = tid >> 6;           // 0..3
    const int lrow = lane >> 5;          // 0..1
    const int lcol = (lane & 31) * 4;    // 0..124
    const int tx = tid & 15;
    const int ty = tid >> 4;
    const int d0 = dblk * 128;
    const int p0 = pblk * 128;

    const float* xn = x + (size_t)n * C * HW;
    const int pcol = min(p0 + lcol, HW - 4);          // clamp: only affects
    const float* aBase = wt + d0 + lcol;              // masked-out columns
    const float* bBase = xn + pcol;

    float acc[8][8];
    #pragma unroll
    for (int j = 0; j < 8; j++)
        #pragma unroll
        for (int i = 0; i < 8; i++) acc[j][i] = 0.f;

    // async prefetch of one 16xK tile pair into buf
    auto prefetch = [&](int c0, int buf) {
        float* a_l = As + buf*2048 + (wv*4)*128;
        float* b_l = Bs + buf*2048 + (wv*4)*128;
        const float* a_g = aBase + (size_t)(c0 + wv*4 + lrow) * C;
        const float* b_g = bBase + (size_t)(c0 + wv*4 + lrow) * HW;
        GLL(a_g,         a_l);
        GLL(a_g + 2*C,   a_l + 2*128);
        GLL(b_g,         b_l);
        GLL(b_g + 2*HW,  b_l + 2*128);
    };

    auto compute = [&](const float* __restrict__ A, const float* __restrict__ B) {
        #pragma unroll
        for (int k = 0; k < 16; k++) {
            float4 al = *(const float4*)&A[k*128 + ty*4];
            float4 ah = *(const float4*)&A[k*128 + 64 + ty*4];
            float4 bl = *(const float4*)&B[k*128 + tx*4];
            float4 bh = *(const float4*)&B[k*128 + 64 + tx*4];
            float a8[8] = {al.x, al.y, al.z, al.w, ah.x, ah.y, ah.z, ah.w};
            float b8[8] = {bl.x, bl.y, bl.z, bl.w, bh.x, bh.y, bh.z, bh.w};
            #pragma unroll
            for (int j = 0; j < 8; j++)
                #pragma unroll
                for (int i = 0; i < 8; i++)
                    acc[j][i] = fmaf(a8[j], b8[i], acc[j][i]);
        }
    };

    constexpr int NIT = C / 16;   // always even
    prefetch(0, 0);
    #pragma unroll 1
    for (int i = 0; i < NIT; i += 2) {
        __syncthreads();                       // buf0 ready (vmcnt drained)
        prefetch((i+1)*16, 1);
        compute(As, Bs);
        __syncthreads();                       // buf1 ready, buf0 compute done
        if (i + 2 < NIT) prefetch((i+2)*16, 0);
        compute(As + 2048, Bs + 2048);
    }

    // epilogue: + sh[d], SiLU, store
    const bool full = (p0 + 128 <= HW);
    #pragma unroll
    for (int j = 0; j < 8; j++) {
        int d = d0 + ((j < 4) ? (ty*4 + j) : (64 + ty*4 + j - 4));
        float sc = g[d] * rsqrtf(vv[d] + 1e-5f);
        float sh = bb[d] - mm[d] * sc;
        float* dst = pf + ((size_t)n * C + d) * HW;
        float o[8];
        #pragma unroll
        for (int i = 0; i < 8; i++) {
            float y = acc[j][i] + sh;
            o[i] = y / (1.f + __expf(-y));
        }
        if (full) {
            *(float4*)&dst[p0 + tx*4]      = make_float4(o[0], o[1], o[2], o[3]);
            *(float4*)&dst[p0 + 64 + tx*4] = make_float4(o[4], o[5], o[6], o[7]);
        } else {
            #pragma unroll
            for (int i = 0; i < 8; i++) {
                int p = p0 + ((i < 4) ? (tx*4 + i) : (64 + tx*4 + i - 4));
                if (p < HW) dst[p] = o[i];
            }
        }
    }
}

__global__ __launch_bounds__(256)
void conv_all(const float* x0, const float* wt0, const float* g0, const float* b0,
              const float* m0, const float* v0, float* pf0,
              const float* x1, const float* wt1, const float* g1, const float* b1,
              const float* m1, const float* v1, float* pf1,
              const float* x2, const float* wt2, const float* g2, const float* b2,
              const float* m2, const float* v2, float* pf2,
              const int* __restrict__ needed)
{
    __shared__ __align__(16) float As[2*16*128];
    __shared__ __align__(16) float Bs[2*16*128];
    const int bid = blockIdx.x;
    if (bid < 256) {                 // level 2: 16n x 4d x 4p  (longest blocks first)
        int n = bid >> 4, d = (bid >> 2) & 3, p = bid & 3;
        if (!needed[n]) return;
        conv_tile<512, 400>(x2, wt2, g2, b2, m2, v2, pf2, n, d, p, As, Bs);
    } else if (bid < 768) {          // level 1: 16n x 2d x 16p (13 real)
        int rel = bid - 256;
        int n = rel >> 5, d = (rel >> 4) & 1, p = rel & 15;
        if (p >= 13 || !needed[n]) return;
        conv_tile<256, 1600>(x1, wt1, g1, b1, m1, v1, pf1, n, d, p, As, Bs);
    } else {                         // level 0: 16n x 1d x 64p (50 real)
        int rel = bid - 768;
        int n = rel >> 6, p = rel & 63;
        if (p >= 50 || !needed[n]) return;
        conv_tile<128, 6400>(x0, wt0, g0, b0, m0, v0, pf0, n, 0, p, As, Bs);
    }
}

// ---------------------------------------------------------------------------
// Fused local-corr(81 offsets) + softmax + mlp dot.  (unchanged from round 2)
// One block per (b, c); both future frames share each f1 window load.
// 384 threads = 6 waves = (2 pixel halves) x (3 ky-triples).
// ---------------------------------------------------------------------------
template<int C, int H, int W, int STEP>
__global__ __launch_bounds__(384)
void corr_kernel(const float* __restrict__ pf, const int* __restrict__ idx,
                 const float* __restrict__ mlp, float* __restrict__ out)
{
    constexpr int PAD  = 4 * STEP;
    constexpr int PW   = W + 2*PAD;
    constexpr int PH   = H + 2*PAD;
    constexpr int HW   = H * W;
    constexpr int QUADS = HW / 4;
    constexpr int QPH   = QUADS / 2;
    constexpr int ITERS = (QPH + 63) / 64;
    constexpr int WINF  = 8*STEP + 4;
    constexpr int WIN4  = WINF / 4;

    __shared__ __align__(16) float f1s[PH*PW];
    __shared__ float part[2][2][81];
    __shared__ float simC[2][81];

    const int c    = blockIdx.x;
    const int b    = blockIdx.y;
    const int tid  = threadIdx.x;
    const int lane = tid & 63;
    const int wave = tid >> 6;
    const int ph   = wave / 3;
    const int kys  = wave % 3;

    const float* f1  = pf + ((size_t)(b*TPP + TPP-1) * C + c) * HW;
    const float* f2a = pf + ((size_t)idx[b*TFF + 0] * C + c) * HW;
    const float* f2b = pf + ((size_t)idx[b*TFF + 1] * C + c) * HW;

    for (int i = tid; i < PH*PW; i += 384) {
        int y = i / PW - PAD;
        int x = i % PW - PAD;
        float val = 0.f;
        if (y >= 0 && y < H && x >= 0 && x < W) val = f1[y*W + x];
        f1s[i] = val;
    }
    __syncthreads();

    float acc[2][3][9];
    #pragma unroll
    for (int f = 0; f < 2; f++)
        #pragma unroll
        for (int j = 0; j < 3; j++)
            #pragma unroll
            for (int k = 0; k < 9; k++) acc[f][j][k] = 0.f;

    for (int it = 0; it < ITERS; it++) {
        int q = ph*QPH + it*64 + lane;
        if (q < (ph+1)*QPH) {
            int p4 = q * 4;
            int h  = p4 / W;
            int w0 = p4 % W;
            float4 fa = *(const float4*)(f2a + p4);
            float4 fb = *(const float4*)(f2b + p4);
            #pragma unroll
            for (int j = 0; j < 3; j++) {
                int ky = kys*3 + j;
                const float* row = &f1s[(h + PAD + (ky-4)*STEP) * PW + w0];
                float win[WINF];
                #pragma unroll
                for (int t = 0; t < WIN4; t++)
                    *(float4*)&win[t*4] = *(const float4*)&row[t*4];
                #pragma unroll
                for (int kx = 0; kx < 9; kx++) {
                    float w0v = win[kx*STEP+0], w1v = win[kx*STEP+1];
                    float w2v = win[kx*STEP+2], w3v = win[kx*STEP+3];
                    float sa = acc[0][j][kx];
                    sa = fmaf(w0v, fa.x, sa); sa = fmaf(w1v, fa.y, sa);
                    sa = fmaf(w2v, fa.z, sa); sa = fmaf(w3v, fa.w, sa);
                    acc[0][j][kx] = sa;
                    float sb = acc[1][j][kx];
                    sb = fmaf(w0v, fb.x, sb); sb = fmaf(w1v, fb.y, sb);
                    sb = fmaf(w2v, fb.z, sb); sb = fmaf(w3v, fb.w, sb);
                    acc[1][j][kx] = sb;
                }
            }
        }
    }

    #pragma unroll
    for (int f = 0; f < 2; f++)
        #pragma unroll
        for (int j = 0; j < 3; j++)
            #pragma unroll
            for (int kx = 0; kx < 9; kx++) {
                float v = acc[f][j][kx];
                v += __shfl_xor(v, 32);
                v += __shfl_xor(v, 16);
                v += __shfl_xor(v, 8);
                v += __shfl_xor(v, 4);
                v += __shfl_xor(v, 2);
                v += __shfl_xor(v, 1);
                if (lane == 0) part[ph][f][(kys*3 + j)*9 + kx] = v;
            }
    __syncthreads();
    if (tid < 162) {
        int f = tid / 81, k = tid % 81;
        simC[f][k] = part[0][f][k] + part[1][f][k];
    }
    __syncthreads();

    if (tid < 128) {
        int f = wave;
        float v0 = simC[f][lane];
        float v1 = (lane + 64 < 81) ? simC[f][lane + 64] : -INFINITY;
        float mx = fmaxf(v0, v1);
        #pragma unroll
        for (int m = 32; m; m >>= 1) mx = fmaxf(mx, __shfl_xor(mx, m));
        float e0 = __expf(v0 - mx);
        float e1 = (lane + 64 < 81) ? __expf(v1 - mx) : 0.f;
        float ssum = e0 + e1;
        float dsum = e0 * mlp[lane] + ((lane + 64 < 81) ? e1 * mlp[lane + 64] : 0.f);
        #pragma unroll
        for (int m = 32; m; m >>= 1) {
            ssum += __shfl_xor(ssum, m);
            dsum += __shfl_xor(dsum, m);
        }
        if (lane == 0) out[(size_t)(b*TFF + f) * C + c] = dsum / ssum;
    }
}

// ---------------------------------------------------------------------------
extern "C" void kernel_launch(void* const* d_in, const int* in_sizes, int n_in,
                              void* d_out, int out_size, void* d_ws, size_t ws_size,
                              hipStream_t stream)
{
    const float* feat0 = (const float*)d_in[0];
    const float* w0 = (const float*)d_in[1];
    const float* g0 = (const float*)d_in[2];
    const float* b0 = (const float*)d_in[3];
    const float* m0 = (const float*)d_in[4];
    const float* v0 = (const float*)d_in[5];
    const float* feat1 = (const float*)d_in[6];
    const float* w1 = (const float*)d_in[7];
    const float* g1 = (const float*)d_in[8];
    const float* b1 = (const float*)d_in[9];
    const float* m1 = (const float*)d_in[10];
    const float* v1 = (const float*)d_in[11];
    const float* feat2 = (const float*)d_in[12];
    const float* w2 = (const float*)d_in[13];
    const float* g2 = (const float*)d_in[14];
    const float* b2 = (const float*)d_in[15];
    const float* m2 = (const float*)d_in[16];
    const float* v2 = (const float*)d_in[17];
    const float* mlp = (const float*)d_in[18];
    const int* pci = (const int*)d_in[19];
    const int* fci = (const int*)d_in[20];

    float* out = (float*)d_out;

    // workspace layout
    int* idxp    = (int*)d_ws;        // 8
    int* neededp = idxp + 8;          // 16
    float* wt0 = (float*)((char*)d_ws + 256);
    float* wt1 = wt0 + 128*128;
    float* wt2 = wt1 + 256*256;
    float* pf0 = wt2 + 512*512;
    float* pf1 = pf0 + (size_t)NIMG * 128 * 6400;
    float* pf2 = pf1 + (size_t)NIMG * 256 * 1600;

    idx_kernel<<<1, 64, 0, stream>>>(pci, fci, idxp, neededp);
    wprep_kernel<<<336, 256, 0, stream>>>(w0, g0, v0, wt0,
                                          w1, g1, v1, wt1,
                                          w2, g2, v2, wt2);

    // all conv levels in one dispatch (L2 first: longest blocks)
    conv_all<<<1792, 256, 0, stream>>>(
        feat0, wt0, g0, b0, m0, v0, pf0,
        feat1, wt1, g1, b1, m1, v1, pf1,
        feat2, wt2, g2, b2, m2, v2, pf2,
        neededp);

    // fused corr + softmax + mlp (one block per (b,c), both frames)
    corr_kernel<128, 80, 80, 4><<<dim3(128, BB), 384, 0, stream>>>(
        pf0, idxp, mlp, out);
    corr_kernel<256, 40, 40, 2><<<dim3(256, BB), 384, 0, stream>>>(
        pf1, idxp, mlp, out + (size_t)NF * 128);
    corr_kernel<512, 20, 20, 1><<<dim3(512, BB), 384, 0, stream>>>(
        pf2, idxp, mlp, out + (size_t)NF * (128 + 256));
}

// Round 4
// 432.065 us; speedup vs baseline: 1.2557x; 1.2557x over previous
//
#include <hip/hip_runtime.h>
#include <hip/hip_bf16.h>
#include <math.h>

// Problem constants (fixed by setup_inputs)
#define BB 4
#define TPP 4
#define TFF 2
#define NIMG (BB*TPP)   // 16
#define NF (BB*TFF)     // 8

typedef __attribute__((ext_vector_type(8))) short bf16x8;
typedef __attribute__((ext_vector_type(4))) float f32x4;
#define MFMA16(a,b,c) __builtin_amdgcn_mfma_f32_16x16x32_bf16(a,b,c,0,0,0)

// async global->LDS copy, 16B per lane; LDS dest = wave-uniform base + lane*16
#define GLL(gaddr, laddr) __builtin_amdgcn_global_load_lds( \
    (const __attribute__((address_space(1))) void*)(gaddr), \
    (__attribute__((address_space(3))) void*)(laddr), 16, 0, 0)

__device__ __forceinline__ unsigned short f2bf(float x) {
    __hip_bfloat16 h = __float2bfloat16(x);
    return *reinterpret_cast<unsigned short*>(&h);
}
__device__ __forceinline__ float bf2f(unsigned short u) {
    unsigned int v = ((unsigned int)u) << 16;
    return __uint_as_float(v);
}

// ---------------------------------------------------------------------------
// Tiny kernel: replicate _interp_indices on device + mark needed past frames.
// ---------------------------------------------------------------------------
__global__ void idx_kernel(const int* __restrict__ pci, const int* __restrict__ fci,
                           int* __restrict__ idx, int* __restrict__ needed)
{
    if (threadIdx.x == 0 && blockIdx.x == 0) {
        for (int n = 0; n < BB*TPP; n++) needed[n] = 0;
        for (int i = 0; i < BB; i++) {
            needed[i*TPP + TPP-1] = 1;              // f1 frame always needed
            int p_pos = TPP - 2;
            for (int j = 0; j < TFF; j++) {
                int f = fci[i*TFF + j];
                while (p_pos >= 0) {
                    if (p_pos == 0 || f < -pci[i*TPP + p_pos - 1]) {
                        idx[i*TFF + j] = p_pos + i*TPP;
                        needed[p_pos + i*TPP] = 1;
                        break;
                    }
                    p_pos--;
                }
            }
        }
    }
}

// ---------------------------------------------------------------------------
// Weight prep: split W[d][c]*scale[d] into bf16 hi/lo, stored in MFMA
// A-fragment order: frag[ct*DT + dt][lane][j] where lane=(k>>3)*16+m, j=k&7,
// m = d%16, k = c within 32-wide k-tile.  Conv A-staging becomes pure GLL.
// ---------------------------------------------------------------------------
template<int C>
__device__ __forceinline__ void wtile_frag(const float* __restrict__ w,
                                           const float* __restrict__ g,
                                           const float* __restrict__ v,
                                           unsigned short* __restrict__ whi,
                                           unsigned short* __restrict__ wlo, int tile)
{
    constexpr int DT = C/16;
    const int ct = tile / DT, dt = tile % DT;
    const int t = threadIdx.x;
    const size_t base = (size_t)tile * 512;
    #pragma unroll
    for (int e = 0; e < 2; e++) {
        int pos = t*2 + e;                 // 0..511
        int lane = pos >> 3, j = pos & 7;
        int m = lane & 15, q = lane >> 4;
        int d = dt*16 + m, c = ct*32 + q*8 + j;
        float sc = g[d] * rsqrtf(v[d] + 1e-5f);
        float x = w[(size_t)d*C + c] * sc;
        unsigned short hi = f2bf(x);
        float lof = x - bf2f(hi);
        whi[base + pos] = hi;
        wlo[base + pos] = f2bf(lof);
    }
}

__global__ __launch_bounds__(256)
void wprep_kernel(const float* w0, const float* g0, const float* b0, const float* m0, const float* v0,
                  unsigned short* whi0, unsigned short* wlo0, float* sh0,
                  const float* w1, const float* g1, const float* b1, const float* m1, const float* v1,
                  unsigned short* whi1, unsigned short* wlo1, float* sh1,
                  const float* w2, const float* g2, const float* b2, const float* m2, const float* v2,
                  unsigned short* whi2, unsigned short* wlo2, float* sh2)
{
    int bid = blockIdx.x;
    if (bid < 32)        wtile_frag<128>(w0, g0, v0, whi0, wlo0, bid);
    else if (bid < 160)  wtile_frag<256>(w1, g1, v1, whi1, wlo1, bid - 32);
    else if (bid < 672)  wtile_frag<512>(w2, g2, v2, whi2, wlo2, bid - 160);
    else {
        for (int i = threadIdx.x; i < 896; i += 256) {
            if (i < 128)      { int d=i;     float sc=g0[d]*rsqrtf(v0[d]+1e-5f); sh0[d]=b0[d]-m0[d]*sc; }
            else if (i < 384) { int d=i-128; float sc=g1[d]*rsqrtf(v1[d]+1e-5f); sh1[d]=b1[d]-m1[d]*sc; }
            else              { int d=i-384; float sc=g2[d]*rsqrtf(v2[d]+1e-5f); sh2[d]=b2[d]-m2[d]*sc; }
        }
    }
}

// ---------------------------------------------------------------------------
// MFMA conv (bf16x3 split): 128(d) x 128(p) per block, K-tile 32.
// A = pre-split fragment-ordered weights (GLL direct to LDS).
// B = X split hi/lo during staging, written in fragment order (b128, no
// conflicts: readback is lane-contiguous 16B).
// Verified layouts (m89/m97): A[m=lane&15][k=(lane>>4)*8+j],
// B[n=lane&15][k-contig], D: col=lane&15, row=(lane>>4)*4+reg.
// ---------------------------------------------------------------------------
template<int C, int HW>
__device__ __forceinline__ void conv_mfma_tile(
    const float* __restrict__ x,
    const unsigned short* __restrict__ whi,
    const unsigned short* __restrict__ wlo,
    const float* __restrict__ sh,
    float* __restrict__ pf,
    int n, int dblk, int pblk,
    unsigned short* __restrict__ Ahi, unsigned short* __restrict__ Alo,
    unsigned short* __restrict__ Bhi, unsigned short* __restrict__ Blo)
{
    constexpr int DT = C/16;
    const int tid  = threadIdx.x;
    const int lane = tid & 63;
    const int wv   = tid >> 6;
    const int d0 = dblk*128, p0 = pblk*128;
    const float* xn = x + (size_t)n * C * HW;
    const int wdt = (wv >> 1) * 4;     // wave's d-tile base (of 8 local)
    const int wpt = (wv & 1) * 4;      // wave's p-tile base (of 8 local)
    const int kb  = (lane >> 4) * 8;   // fragment k base for staging
    const int pn  = lane & 15;         // fragment n/col index

    f32x4 acc[4][4];
    #pragma unroll
    for (int i = 0; i < 4; i++)
        #pragma unroll
        for (int j = 0; j < 4; j++)
            acc[i][j] = f32x4{0.f, 0.f, 0.f, 0.f};

    for (int ct = 0; ct < C/32; ct++) {
        __syncthreads();     // previous tile's LDS reads complete
        // ---- A staging: pure async copy (fragment-ordered in global) ----
        {
            const size_t gb = ((size_t)ct * DT + dblk*8) * 512 + (size_t)lane*8;
            const unsigned short* ghi = whi + gb;
            const unsigned short* glo = wlo + gb;
            GLL(ghi + (size_t)wv*512,     Ahi + wv*512);
            GLL(ghi + (size_t)(wv+4)*512, Ahi + (wv+4)*512);
            GLL(glo + (size_t)wv*512,     Alo + wv*512);
            GLL(glo + (size_t)(wv+4)*512, Alo + (wv+4)*512);
        }
        // ---- B staging: read fp32, split hi/lo, write fragment-ordered ----
        #pragma unroll
        for (int e = 0; e < 2; e++) {
            int pt = e*4 + (tid >> 6);
            int pp = p0 + pt*16 + pn;
            int pc = pp < HW ? pp : HW-1;          // clamp: affects only masked cols
            const float* src = xn + (size_t)(ct*32 + kb) * HW + pc;
            bf16x8 h8, l8;
            #pragma unroll
            for (int j = 0; j < 8; j++) {
                float xv = src[(size_t)j * HW];
                unsigned short hi = f2bf(xv);
                h8[j] = (short)hi;
                l8[j] = (short)f2bf(xv - bf2f(hi));
            }
            int slot = pt*64 + lane;
            *(bf16x8*)(Bhi + slot*8) = h8;
            *(bf16x8*)(Blo + slot*8) = l8;
        }
        __syncthreads();     // GLL drained (vmcnt) + B writes visible
        // ---- MFMA: 16 output tiles/wave x 3 split terms ----
        bf16x8 bh[4], bl[4];
        #pragma unroll
        for (int j = 0; j < 4; j++) {
            bh[j] = *(const bf16x8*)(Bhi + (wpt+j)*512 + lane*8);
            bl[j] = *(const bf16x8*)(Blo + (wpt+j)*512 + lane*8);
        }
        #pragma unroll
        for (int i = 0; i < 4; i++) {
            bf16x8 ah = *(const bf16x8*)(Ahi + (wdt+i)*512 + lane*8);
            bf16x8 al = *(const bf16x8*)(Alo + (wdt+i)*512 + lane*8);
            #pragma unroll
            for (int j = 0; j < 4; j++) {
                acc[i][j] = MFMA16(ah, bh[j], acc[i][j]);
                acc[i][j] = MFMA16(al, bh[j], acc[i][j]);
                acc[i][j] = MFMA16(ah, bl[j], acc[i][j]);
            }
        }
    }

    // ---- epilogue: + shift, SiLU, store (D: col=lane&15, row=quad*4+r) ----
    const int rowq = (lane >> 4) * 4;
    #pragma unroll
    for (int i = 0; i < 4; i++) {
        #pragma unroll
        for (int r = 0; r < 4; r++) {
            int d = d0 + (wdt+i)*16 + rowq + r;
            float shd = sh[d];
            float* dst = pf + ((size_t)n * C + d) * HW;
            #pragma unroll
            for (int j = 0; j < 4; j++) {
                int p = p0 + (wpt+j)*16 + pn;
                float y = acc[i][j][r] + shd;
                float o = y / (1.f + __expf(-y));
                if (p < HW) dst[p] = o;
            }
        }
    }
}

__global__ __launch_bounds__(256, 2)
void conv_all(const float* x0, const unsigned short* whi0, const unsigned short* wlo0,
              const float* sh0, float* pf0,
              const float* x1, const unsigned short* whi1, const unsigned short* wlo1,
              const float* sh1, float* pf1,
              const float* x2, const unsigned short* whi2, const unsigned short* wlo2,
              const float* sh2, float* pf2,
              const int* __restrict__ needed)
{
    __shared__ __align__(16) unsigned short Ahi[8*512];
    __shared__ __align__(16) unsigned short Alo[8*512];
    __shared__ __align__(16) unsigned short Bhi[8*512];
    __shared__ __align__(16) unsigned short Blo[8*512];
    const int bid = blockIdx.x;
    if (bid < 256) {                  // level 2: 16n x 4d x 4p (longest first)
        int n = bid >> 4, d = (bid >> 2) & 3, p = bid & 3;
        if (!needed[n]) return;
        conv_mfma_tile<512, 400>(x2, whi2, wlo2, sh2, pf2, n, d, p, Ahi, Alo, Bhi, Blo);
    } else if (bid < 672) {           // level 1: 16n x 2d x 13p
        int rel = bid - 256;
        int n = rel / 26, rem = rel % 26;
        int d = rem / 13, p = rem % 13;
        if (!needed[n]) return;
        conv_mfma_tile<256, 1600>(x1, whi1, wlo1, sh1, pf1, n, d, p, Ahi, Alo, Bhi, Blo);
    } else {                          // level 0: 16n x 1d x 50p
        int rel = bid - 672;
        int n = rel / 50, p = rel % 50;
        if (!needed[n]) return;
        conv_mfma_tile<128, 6400>(x0, whi0, wlo0, sh0, pf0, n, 0, p, Ahi, Alo, Bhi, Blo);
    }
}

// ---------------------------------------------------------------------------
// Fused local-corr(81) + softmax + mlp dot, all 3 levels in ONE dispatch.
// Per block (b,c): both future frames share each f1 window load.
// 384 threads = (2 pixel halves) x (3 ky-triples).  Dynamic LDS carve.
// ---------------------------------------------------------------------------
#define MAXPLANE 12544   // 112*112 (level-0 padded plane)

template<int C, int H, int W, int STEP>
__device__ __forceinline__ void corr_tile(const float* __restrict__ pf,
                                          const int* __restrict__ idx,
                                          const float* __restrict__ mlp,
                                          float* __restrict__ out,
                                          int c, int b, float* __restrict__ smem)
{
    constexpr int PAD  = 4 * STEP;
    constexpr int PW   = W + 2*PAD;
    constexpr int PH   = H + 2*PAD;
    constexpr int HW   = H * W;
    constexpr int QPH   = (HW/4) / 2;
    constexpr int ITERS = (QPH + 63) / 64;
    constexpr int WINF  = 8*STEP + 4;
    constexpr int WIN4  = WINF / 4;

    float* f1s  = smem;                    // padded plane
    float* part = smem + MAXPLANE;         // [2][2][81]
    float* simC = part + 324;              // [2][81]

    const int tid  = threadIdx.x;
    const int lane = tid & 63;
    const int wave = tid >> 6;
    const int ph   = wave / 3;
    const int kys  = wave % 3;

    const float* f1  = pf + ((size_t)(b*TPP + TPP-1) * C + c) * HW;
    const float* f2a = pf + ((size_t)idx[b*TFF + 0] * C + c) * HW;
    const float* f2b = pf + ((size_t)idx[b*TFF + 1] * C + c) * HW;

    for (int i = tid; i < PH*PW; i += 384) {
        int y = i / PW - PAD;
        int x = i % PW - PAD;
        float val = 0.f;
        if (y >= 0 && y < H && x >= 0 && x < W) val = f1[y*W + x];
        f1s[i] = val;
    }
    __syncthreads();

    float acc[2][3][9];
    #pragma unroll
    for (int f = 0; f < 2; f++)
        #pragma unroll
        for (int j = 0; j < 3; j++)
            #pragma unroll
            for (int k = 0; k < 9; k++) acc[f][j][k] = 0.f;

    for (int it = 0; it < ITERS; it++) {
        int q = ph*QPH + it*64 + lane;
        if (q < (ph+1)*QPH) {
            int p4 = q * 4;
            int h  = p4 / W;
            int w0 = p4 % W;
            float4 fa = *(const float4*)(f2a + p4);
            float4 fb = *(const float4*)(f2b + p4);
            #pragma unroll
            for (int j = 0; j < 3; j++) {
                int ky = kys*3 + j;
                const float* row = &f1s[(h + PAD + (ky-4)*STEP) * PW + w0];
                float win[WINF];
                #pragma unroll
                for (int t = 0; t < WIN4; t++)
                    *(float4*)&win[t*4] = *(const float4*)&row[t*4];
                #pragma unroll
                for (int kx = 0; kx < 9; kx++) {
                    float w0v = win[kx*STEP+0], w1v = win[kx*STEP+1];
                    float w2v = win[kx*STEP+2], w3v = win[kx*STEP+3];
                    float sa = acc[0][j][kx];
                    sa = fmaf(w0v, fa.x, sa); sa = fmaf(w1v, fa.y, sa);
                    sa = fmaf(w2v, fa.z, sa); sa = fmaf(w3v, fa.w, sa);
                    acc[0][j][kx] = sa;
                    float sb = acc[1][j][kx];
                    sb = fmaf(w0v, fb.x, sb); sb = fmaf(w1v, fb.y, sb);
                    sb = fmaf(w2v, fb.z, sb); sb = fmaf(w3v, fb.w, sb);
                    acc[1][j][kx] = sb;
                }
            }
        }
    }

    #pragma unroll
    for (int f = 0; f < 2; f++)
        #pragma unroll
        for (int j = 0; j < 3; j++)
            #pragma unroll
            for (int kx = 0; kx < 9; kx++) {
                float v = acc[f][j][kx];
                v += __shfl_xor(v, 32);
                v += __shfl_xor(v, 16);
                v += __shfl_xor(v, 8);
                v += __shfl_xor(v, 4);
                v += __shfl_xor(v, 2);
                v += __shfl_xor(v, 1);
                if (lane == 0) part[(ph*2 + f)*81 + (kys*3 + j)*9 + kx] = v;
            }
    __syncthreads();
    if (tid < 162) {
        int f = tid / 81, k = tid % 81;
        simC[f*81 + k] = part[(0*2 + f)*81 + k] + part[(1*2 + f)*81 + k];
    }
    __syncthreads();

    if (tid < 128) {
        int f = wave;
        float v0 = simC[f*81 + lane];
        float v1 = (lane + 64 < 81) ? simC[f*81 + lane + 64] : -INFINITY;
        float mx = fmaxf(v0, v1);
        #pragma unroll
        for (int m = 32; m; m >>= 1) mx = fmaxf(mx, __shfl_xor(mx, m));
        float e0 = __expf(v0 - mx);
        float e1 = (lane + 64 < 81) ? __expf(v1 - mx) : 0.f;
        float ssum = e0 + e1;
        float dsum = e0 * mlp[lane] + ((lane + 64 < 81) ? e1 * mlp[lane + 64] : 0.f);
        #pragma unroll
        for (int m = 32; m; m >>= 1) {
            ssum += __shfl_xor(ssum, m);
            dsum += __shfl_xor(dsum, m);
        }
        if (lane == 0) out[(size_t)(b*TFF + f) * C + c] = dsum / ssum;
    }
}

__global__ __launch_bounds__(384)
void corr_all(const float* __restrict__ pf0, const float* __restrict__ pf1,
              const float* __restrict__ pf2, const int* __restrict__ idx,
              const float* __restrict__ mlp, float* __restrict__ out)
{
    extern __shared__ float smem[];
    const int bid = blockIdx.x;
    if (bid < 512) {                       // level 0 (heaviest first)
        corr_tile<128, 80, 80, 4>(pf0, idx, mlp, out, bid & 127, bid >> 7, smem);
    } else if (bid < 1536) {               // level 1
        int r = bid - 512;
        corr_tile<256, 40, 40, 2>(pf1, idx, mlp, out + (size_t)NF*128, r & 255, r >> 8, smem);
    } else {                               // level 2
        int r = bid - 1536;
        corr_tile<512, 20, 20, 1>(pf2, idx, mlp, out + (size_t)NF*(128+256), r & 511, r >> 9, smem);
    }
}

// ---------------------------------------------------------------------------
extern "C" void kernel_launch(void* const* d_in, const int* in_sizes, int n_in,
                              void* d_out, int out_size, void* d_ws, size_t ws_size,
                              hipStream_t stream)
{
    const float* feat0 = (const float*)d_in[0];
    const float* w0 = (const float*)d_in[1];
    const float* g0 = (const float*)d_in[2];
    const float* b0 = (const float*)d_in[3];
    const float* m0 = (const float*)d_in[4];
    const float* v0 = (const float*)d_in[5];
    const float* feat1 = (const float*)d_in[6];
    const float* w1 = (const float*)d_in[7];
    const float* g1 = (const float*)d_in[8];
    const float* b1 = (const float*)d_in[9];
    const float* m1 = (const float*)d_in[10];
    const float* v1 = (const float*)d_in[11];
    const float* feat2 = (const float*)d_in[12];
    const float* w2 = (const float*)d_in[13];
    const float* g2 = (const float*)d_in[14];
    const float* b2 = (const float*)d_in[15];
    const float* m2 = (const float*)d_in[16];
    const float* v2 = (const float*)d_in[17];
    const float* mlp = (const float*)d_in[18];
    const int* pci = (const int*)d_in[19];
    const int* fci = (const int*)d_in[20];

    float* out = (float*)d_out;

    // workspace layout
    char* base = (char*)d_ws;
    int* idxp    = (int*)base;                 // 8
    int* neededp = idxp + 8;                   // 16
    float* sh0 = (float*)(base + 256);         // 128
    float* sh1 = sh0 + 128;                    // 256
    float* sh2 = sh1 + 256;                    // 512
    unsigned short* whi0 = (unsigned short*)(sh2 + 512);
    unsigned short* wlo0 = whi0 + 128*128;
    unsigned short* whi1 = wlo0 + 128*128;
    unsigned short* wlo1 = whi1 + 256*256;
    unsigned short* whi2 = wlo1 + 256*256;
    unsigned short* wlo2 = whi2 + 512*512;
    float* pf0 = (float*)(wlo2 + 512*512);
    float* pf1 = pf0 + (size_t)NIMG * 128 * 6400;
    float* pf2 = pf1 + (size_t)NIMG * 256 * 1600;

    idx_kernel<<<1, 64, 0, stream>>>(pci, fci, idxp, neededp);
    wprep_kernel<<<673, 256, 0, stream>>>(
        w0, g0, b0, m0, v0, whi0, wlo0, sh0,
        w1, g1, b1, m1, v1, whi1, wlo1, sh1,
        w2, g2, b2, m2, v2, whi2, wlo2, sh2);

    // all conv levels, one dispatch (L2's K=512 blocks first)
    conv_all<<<1472, 256, 0, stream>>>(
        feat0, whi0, wlo0, sh0, pf0,
        feat1, whi1, wlo1, sh1, pf1,
        feat2, whi2, wlo2, sh2, pf2,
        neededp);

    // all corr levels, one dispatch (dynamic LDS: plane + partials)
    corr_all<<<3584, 384, (MAXPLANE + 324 + 162) * sizeof(float), stream>>>(
        pf0, pf1, pf2, idxp, mlp, out);
}